// Round 12
// baseline (474.312 us; speedup 1.0000x reference)
//
#include <hip/hip_runtime.h>

// FPS: dense scan kernel + ONE cooperative kernel for steps 2..9.
// B=64, N=262144, NPOINT=10.
// scan1 (16384 blocks): full pass vs point 0 -> per-quarter (1024-pt) records
//   ub (stale max), cand (exact dmin of uidx), uidx, point COORDS; block c==0
//   also zeroes win/bar comm state (replay-safe, no memset dispatch).
// fps_steps (512 blocks = 64 batches x 8, bounds(256,2) -- the PROVEN
//   cooperative config; round-11's 1024/min4 failed to launch): each block
//   owns 32 quarter-records in LDS. Per step: one per-batch RMW spin barrier
//   (round-8-proven coherent), ONE RMW read resolves prev winner, gather-free
//   cand refresh -> block-local LB (realized value => valid), survivors
//   (staleUB >= LB, strict <) rescanned wave-parallel, posts via packed
//   (valbits<<32)|(~idx) atomicMax -> max val, lowest idx, deterministic.

#define NPOINT 10
#define NB     64
#define NPTS   262144
#define QN     256           // quarters per batch
#define QCH    1024          // points per quarter
#define TPB    256
#define BPB    8             // coop blocks per batch
#define QPB    32            // quarters per coop block
#define INIT_DIST 1e10f

// Strict IEEE, reference association order ((dx^2+dy^2)+dz^2), no contraction.
__device__ __forceinline__ float sqdist(float x, float y, float z,
                                        float cx, float cy, float cz) {
    float dx = x - cx, dy = y - cy, dz = z - cz;
    return __fadd_rn(__fadd_rn(__fmul_rn(dx, dx), __fmul_rn(dy, dy)),
                     __fmul_rn(dz, dz));
}

__device__ __forceinline__ unsigned long long packvi(float v, int i) {
    return ((unsigned long long)__float_as_uint(v) << 32) |
           (unsigned)(0xFFFFFFFFu - (unsigned)i);
}
__device__ __forceinline__ int unpack_idx(unsigned long long w) {
    return (int)(0xFFFFFFFFu - (unsigned)(w & 0xFFFFFFFFull));
}

// 64-lane shfl argmax (max val, ties -> lowest idx); result in lane 0.
__device__ __forceinline__ void wave_argmax(float& v, int& i) {
    #pragma unroll
    for (int off = 32; off > 0; off >>= 1) {
        float ov = __shfl_down(v, off); int oi = __shfl_down(i, off);
        if (ov > v || (ov == v && oi < i)) { v = ov; i = oi; }
    }
}

// ---- Kernel A: dense scan vs point 0 -> quarter records; zero comm state.
__global__ __launch_bounds__(TPB) void fps_scan1(
    const float* __restrict__ xyz,
    float* __restrict__ ub, float* __restrict__ cd, int* __restrict__ ui,
    float* __restrict__ px, float* __restrict__ py, float* __restrict__ pz,
    unsigned long long* __restrict__ win, unsigned* __restrict__ bar)
{
    const int c = blockIdx.x, b = blockIdx.y, tid = threadIdx.x;
    const int lane = tid & 63, wv = tid >> 6;
    const float* xyzb = xyz + (size_t)b * NPTS * 3;
    const float c0x = xyzb[0], c0y = xyzb[1], c0z = xyzb[2];
    __shared__ float s_v[4];
    __shared__ int   s_i[4];

    if (c == 0) {               // pre-coop zeroing (stream-ordered, replay-safe)
        if (tid < NPOINT) win[((size_t)tid * NB + b) * 16] = 0ULL;
        if (tid == NPOINT) bar[b * 32] = 0u;
    }

    const int p0 = c * QCH + tid * 4;
    const float4* src = (const float4*)(xyzb + (size_t)p0 * 3);
    float4 a = src[0], m = src[1], e = src[2];
    float X[4] = {a.x, a.w, m.z, e.y};
    float Y[4] = {a.y, m.x, m.w, e.z};
    float Z[4] = {a.z, m.y, e.x, e.w};
    float bv = -1.0f; int bi = 0;
    #pragma unroll
    for (int j = 0; j < 4; ++j) {
        float d = fminf(INIT_DIST, sqdist(X[j], Y[j], Z[j], c0x, c0y, c0z));
        if (d > bv) { bv = d; bi = p0 + j; }
    }
    wave_argmax(bv, bi);
    if (lane == 0) { s_v[wv] = bv; s_i[wv] = bi; }
    __syncthreads();
    if (tid == 0) {
        float v = s_v[0]; int i = s_i[0];
        #pragma unroll
        for (int w = 1; w < 4; ++w) {
            float ov = s_v[w]; int oi = s_i[w];
            if (ov > v || (ov == v && oi < i)) { v = ov; i = oi; }
        }
        const int o = b * QN + c;
        ub[o] = v; cd[o] = v; ui[o] = i;
        const float* qq = xyzb + (size_t)i * 3;
        px[o] = qq[0]; py[o] = qq[1]; pz[o] = qq[2];
    }
}

// Wave-level exact scan of quarter qid vs centers 0..R-1; result in lane 0.
template <int R>
__device__ __forceinline__ void scanW(const float* __restrict__ xyzb, int qid,
                                      int lane, const float* scx,
                                      const float* scy, const float* scz,
                                      float& outv, int& outi) {
    float cx[R], cy[R], cz[R];
    #pragma unroll
    for (int k = 0; k < R; ++k) { cx[k] = scx[k]; cy[k] = scy[k]; cz[k] = scz[k]; }
    float bestv = -1.0f; int besti = 0;
    const int p0 = qid * QCH + lane * 16;
    #pragma unroll
    for (int grp = 0; grp < 4; ++grp) {
        const float4* src = (const float4*)(xyzb + (size_t)(p0 + grp * 4) * 3);
        float4 a = src[0], m4 = src[1], e = src[2];
        float X[4] = {a.x, a.w, m4.z, e.y};
        float Y[4] = {a.y, m4.x, m4.w, e.z};
        float Z[4] = {a.z, m4.y, e.x, e.w};
        #pragma unroll
        for (int j = 0; j < 4; ++j) {
            float dmin = INIT_DIST;
            #pragma unroll
            for (int k = 0; k < R; ++k)
                dmin = fminf(dmin, sqdist(X[j], Y[j], Z[j], cx[k], cy[k], cz[k]));
            if (dmin > bestv) { bestv = dmin; besti = p0 + grp * 4 + j; }
        }
    }
    wave_argmax(bestv, besti);
    outv = bestv; outi = besti;
}

// ---- Kernel B: cooperative steps 2..9 (512 blocks, proven-launchable).
__global__ __launch_bounds__(TPB, 2) void fps_steps(
    const float* __restrict__ xyz, int* __restrict__ out,
    const float* __restrict__ ub_g, const float* __restrict__ cd_g,
    const int* __restrict__ ui_g, const float* __restrict__ px_g,
    const float* __restrict__ py_g, const float* __restrict__ pz_g,
    unsigned long long* __restrict__ win, unsigned* __restrict__ bar)
{
    const int blk = blockIdx.x;
    const int b = blk / BPB, sub = blk % BPB;
    const int tid = threadIdx.x, lane = tid & 63, wv = tid >> 6;
    const float* xyzb = xyz + (size_t)b * NPTS * 3;
    unsigned* const cnt = bar + b * 32;

    __shared__ float scx[NPOINT], scy[NPOINT], scz[NPOINT];
    __shared__ float l_ub[QPB], l_cd[QPB], l_px[QPB], l_py[QPB], l_pz[QPB];
    __shared__ int   l_ui[QPB];
    __shared__ unsigned s_mask;

    // init: load this block's 32 records (contiguous), post dense winner cand
    if (tid < QPB) {
        const int g0 = b * QN + sub * QPB + tid;
        l_ub[tid] = ub_g[g0]; l_cd[tid] = cd_g[g0]; l_ui[tid] = ui_g[g0];
        l_px[tid] = px_g[g0]; l_py[tid] = py_g[g0]; l_pz[tid] = pz_g[g0];
    }
    if (tid == 0) { scx[0] = xyzb[0]; scy[0] = xyzb[1]; scz[0] = xyzb[2]; }
    __syncthreads();
    if (wv == 0) {
        float v = (lane < QPB) ? l_ub[lane] : -1.0f;
        int   i = (lane < QPB) ? l_ui[lane] : 0x7fffffff;
        wave_argmax(v, i);
        if (lane == 0)
            atomicMax(win + ((size_t)1 * NB + b) * 16, packvi(v, i));
    }
    if (sub == 0 && tid == 0) out[b * NPOINT + 0] = 0;

    int gen = 0;
    for (int r = 2; r < NPOINT; ++r) {
        ++gen;
        __syncthreads();                 // drain ALL waves' posts (R7 lesson)
        if (tid == 0) {
            __threadfence();
            atomicAdd(cnt, 1u);
            const unsigned tgt = (unsigned)(gen * BPB);
            while (atomicAdd(cnt, 0u) < tgt)   // RMW poll: proven coherent (R8)
                __builtin_amdgcn_s_sleep(4);
            __threadfence();
            unsigned long long w =
                atomicMax(win + ((size_t)(r - 1) * NB + b) * 16, 0ULL);
            const int prevIdx = unpack_idx(w);
            const float* pp = xyzb + (size_t)prevIdx * 3;
            scx[r - 1] = pp[0]; scy[r - 1] = pp[1]; scz[r - 1] = pp[2];
            if (sub == 0) out[b * NPOINT + (r - 1)] = prevIdx;
        }
        __syncthreads();

        // gather-free cand refresh + block-local LB + survivor mask (wave 0)
        if (wv == 0) {
            float cdv = -1.0f;
            if (lane < QPB) {
                cdv = fminf(l_cd[lane],
                            sqdist(l_px[lane], l_py[lane], l_pz[lane],
                                   scx[r - 1], scy[r - 1], scz[r - 1]));
                l_cd[lane] = cdv;
            }
            float m = cdv;
            #pragma unroll
            for (int off = 32; off > 0; off >>= 1)
                m = fmaxf(m, __shfl_down(m, off));
            const float lb = __shfl(m, 0);
            const bool flag = (lane < QPB) && (l_ub[lane] >= lb);  // strict <
            const unsigned long long bm = __ballot(flag);
            if (lane == 0) s_mask = (unsigned)bm;
        }
        __syncthreads();
        const unsigned mask = s_mask;

        // survivor rescans, wave-granularity round-robin
        unsigned long long* const wr = win + ((size_t)r * NB + b) * 16;
        int sc = 0;
        for (int q = 0; q < QPB; ++q) {
            if (!((mask >> q) & 1u)) continue;
            if ((sc++ & 3) == wv) {
                const int qid = sub * QPB + q;
                float v; int i;
                switch (r) {
                    case 2: scanW<2>(xyzb, qid, lane, scx, scy, scz, v, i); break;
                    case 3: scanW<3>(xyzb, qid, lane, scx, scy, scz, v, i); break;
                    case 4: scanW<4>(xyzb, qid, lane, scx, scy, scz, v, i); break;
                    case 5: scanW<5>(xyzb, qid, lane, scx, scy, scz, v, i); break;
                    case 6: scanW<6>(xyzb, qid, lane, scx, scy, scz, v, i); break;
                    case 7: scanW<7>(xyzb, qid, lane, scx, scy, scz, v, i); break;
                    case 8: scanW<8>(xyzb, qid, lane, scx, scy, scz, v, i); break;
                    default: scanW<9>(xyzb, qid, lane, scx, scy, scz, v, i); break;
                }
                if (lane == 0) {
                    atomicMax(wr, packvi(v, i));
                    l_ub[q] = v; l_cd[q] = v; l_ui[q] = i;
                    const float* qq = xyzb + (size_t)i * 3;
                    l_px[q] = qq[0]; l_py[q] = qq[1]; l_pz[q] = qq[2];
                }
            }
        }
    }

    // final barrier + decode step-9 winner
    ++gen;
    __syncthreads();
    if (tid == 0) {
        __threadfence();
        atomicAdd(cnt, 1u);
        const unsigned tgt = (unsigned)(gen * BPB);
        while (atomicAdd(cnt, 0u) < tgt)
            __builtin_amdgcn_s_sleep(4);
        __threadfence();
        if (sub == 0) {
            unsigned long long w =
                atomicMax(win + ((size_t)(NPOINT - 1) * NB + b) * 16, 0ULL);
            out[b * NPOINT + (NPOINT - 1)] = unpack_idx(w);
        }
    }
}

extern "C" void kernel_launch(void* const* d_in, const int* in_sizes, int n_in,
                              void* d_out, int out_size, void* d_ws, size_t ws_size,
                              hipStream_t stream) {
    const float* xyz = (const float*)d_in[0];
    int* out = (int*)d_out;
    char* ws = (char*)d_ws;

    float* ub = (float*)(ws + 0);        // 64*256*4 = 64 KB each
    float* cd = (float*)(ws + 65536);
    int*   ui = (int*)  (ws + 131072);
    float* px = (float*)(ws + 196608);
    float* py = (float*)(ws + 262144);
    float* pz = (float*)(ws + 327680);
    unsigned long long* win = (unsigned long long*)(ws + 393216); // 81920 B
    unsigned* bar = (unsigned*)(ws + 475136);                     //  8192 B

    fps_scan1<<<dim3(QN, NB), dim3(TPB), 0, stream>>>(xyz, ub, cd, ui,
                                                      px, py, pz, win, bar);

    void* args[] = {(void*)&xyz, (void*)&out, (void*)&ub, (void*)&cd,
                    (void*)&ui, (void*)&px, (void*)&py, (void*)&pz,
                    (void*)&win, (void*)&bar};
    hipLaunchCooperativeKernel((void*)fps_steps, dim3(NB * BPB), dim3(TPB),
                               args, 0, stream);
}

// Round 13
// 304.121 us; speedup vs baseline: 1.5596x; 1.5596x over previous
//
#include <hip/hip_runtime.h>

// FPS, split-step multi-launch. B=64, N=262144, NPOINT=10.
// Records at 256-pt granularity (1024/batch): ub (stale max), cand (exact
// current dmin of uidx; sequential fminf fold in reference order), uidx,
// point COORDS (gather-free refresh).
// Per step r: stepA (64 blocks) resolves prev winner from win[r-1], writes
// out/sel, refreshes ALL cands ONCE (round-12 lesson: round-10 did this
// 64x redundantly), LB = max cand -> lb[b].  stepB (16x64 blocks, 4 waves
// each owning 16 records) rescans survivors (staleUB >= LB, strict <) at
// wave granularity -> high MLP on the ~3KB survivor reads; posts packed
// (valbits<<32)|(~idx) atomicMax -> max val, lowest idx, deterministic.

#define NPOINT 10
#define NB     64
#define NPTS   262144
#define NR     1024          // records per batch
#define HCH    256           // points per record
#define TPB    256
#define INIT_DIST 1e10f

// Strict IEEE, reference association order ((dx^2+dy^2)+dz^2), no contraction.
__device__ __forceinline__ float sqdist(float x, float y, float z,
                                        float cx, float cy, float cz) {
    float dx = x - cx, dy = y - cy, dz = z - cz;
    return __fadd_rn(__fadd_rn(__fmul_rn(dx, dx), __fmul_rn(dy, dy)),
                     __fmul_rn(dz, dz));
}

__device__ __forceinline__ unsigned long long packvi(float v, int i) {
    return ((unsigned long long)__float_as_uint(v) << 32) |
           (unsigned)(0xFFFFFFFFu - (unsigned)i);
}
__device__ __forceinline__ int unpack_idx(unsigned long long w) {
    return (int)(0xFFFFFFFFu - (unsigned)(w & 0xFFFFFFFFull));
}

__device__ __forceinline__ void wave_argmax(float& v, int& i) {
    #pragma unroll
    for (int off = 32; off > 0; off >>= 1) {
        float ov = __shfl_down(v, off); int oi = __shfl_down(i, off);
        if (ov > v || (ov == v && oi < i)) { v = ov; i = oi; }
    }
}

// Wave scan of record rec (256 pts, 4/lane) vs centers 0..R-1; lane0 result.
template <int R>
__device__ __forceinline__ void scanW(const float* __restrict__ xyzb, int rec,
                                      int lane, const float* scx,
                                      const float* scy, const float* scz,
                                      float& outv, int& outi) {
    float cx[R], cy[R], cz[R];
    #pragma unroll
    for (int k = 0; k < R; ++k) { cx[k] = scx[k]; cy[k] = scy[k]; cz[k] = scz[k]; }
    const int p0 = rec * HCH + lane * 4;
    const float4* src = (const float4*)(xyzb + (size_t)p0 * 3);
    float4 a = src[0], m4 = src[1], e = src[2];
    float X[4] = {a.x, a.w, m4.z, e.y};
    float Y[4] = {a.y, m4.x, m4.w, e.z};
    float Z[4] = {a.z, m4.y, e.x, e.w};
    float bv = -1.0f; int bi = 0;
    #pragma unroll
    for (int j = 0; j < 4; ++j) {
        float dmin = INIT_DIST;
        #pragma unroll
        for (int k = 0; k < R; ++k)
            dmin = fminf(dmin, sqdist(X[j], Y[j], Z[j], cx[k], cy[k], cz[k]));
        if (dmin > bv) { bv = dmin; bi = p0 + j; }
    }
    wave_argmax(bv, bi);
    outv = bv; outi = bi;
}

// ---- scan1: dense pass vs point 0 -> fresh records; zero win slots.
__global__ __launch_bounds__(TPB) void fps_scan1(
    const float* __restrict__ xyz,
    float* __restrict__ ub, float* __restrict__ cd, int* __restrict__ ui,
    float* __restrict__ px, float* __restrict__ py, float* __restrict__ pz,
    unsigned long long* __restrict__ win)
{
    const int g = blockIdx.x, b = blockIdx.y, tid = threadIdx.x;
    const int lane = tid & 63, wv = tid >> 6;
    const float* xyzb = xyz + (size_t)b * NPTS * 3;
    if (g == 0 && tid < NPOINT) win[((size_t)tid * NB + b) * 16] = 0ULL;

    const float c0x = xyzb[0], c0y = xyzb[1], c0z = xyzb[2];
    const int rec = g * 4 + wv;
    const float ax[1] = {c0x}, ay[1] = {c0y}, az[1] = {c0z};
    float v; int i;
    scanW<1>(xyzb, rec, lane, ax, ay, az, v, i);
    if (lane == 0) {
        const int o = b * NR + rec;
        ub[o] = v; cd[o] = v; ui[o] = i;
        const float* qq = xyzb + (size_t)i * 3;
        px[o] = qq[0]; py[o] = qq[1]; pz[o] = qq[2];
    }
}

// ---- stepA<R>: resolve winner R-1, write out/sel, refresh cands, LB.
// R==NPOINT: resolve-only (final output).
template <int R>
__global__ __launch_bounds__(TPB) void fps_stepA(
    const float* __restrict__ xyz, int* __restrict__ out,
    float4* __restrict__ sel,
    const float* __restrict__ ub, float* __restrict__ cd,
    const int* __restrict__ ui,
    const float* __restrict__ px, const float* __restrict__ py,
    const float* __restrict__ pz,
    const unsigned long long* __restrict__ win, float* __restrict__ lb)
{
    const int b = blockIdx.x, tid = threadIdx.x;
    const float* xyzb = xyz + (size_t)b * NPTS * 3;
    __shared__ float s_v[TPB];
    __shared__ int   s_i[TPB];
    __shared__ float s_c[3];

    int prevIdx;
    if constexpr (R == 2) {
        // step-1 winner = argmax over fresh records (exact, lowest-idx ties)
        float v = -1.0f; int i = 0x7fffffff;
        #pragma unroll
        for (int t0 = 0; t0 < NR; t0 += TPB) {
            const int o = b * NR + t0 + tid;
            float u = ub[o]; int j = ui[o];
            if (u > v || (u == v && j < i)) { v = u; i = j; }
        }
        s_v[tid] = v; s_i[tid] = i;
        __syncthreads();
        for (int st = TPB / 2; st > 0; st >>= 1) {
            if (tid < st) {
                float ov = s_v[tid + st]; int oi = s_i[tid + st];
                if (ov > s_v[tid] || (ov == s_v[tid] && oi < s_i[tid])) {
                    s_v[tid] = ov; s_i[tid] = oi;
                }
            }
            __syncthreads();
        }
        prevIdx = s_i[0];
        if (tid == 0) {
            out[b * NPOINT + 0] = 0;
            sel[b * 16 + 0] = make_float4(xyzb[0], xyzb[1], xyzb[2], 0.f);
        }
    } else {
        prevIdx = unpack_idx(win[((size_t)(R - 1) * NB + b) * 16]);
    }

    if (tid == 0) {
        out[b * NPOINT + (R - 1)] = prevIdx;
        const float* pp = xyzb + (size_t)prevIdx * 3;
        s_c[0] = pp[0]; s_c[1] = pp[1]; s_c[2] = pp[2];
        if constexpr (R < NPOINT)
            sel[b * 16 + (R - 1)] = make_float4(pp[0], pp[1], pp[2], 0.f);
    }
    __syncthreads();

    if constexpr (R < NPOINT) {
        const float ccx = s_c[0], ccy = s_c[1], ccz = s_c[2];
        float m = -1.0f;
        #pragma unroll
        for (int t0 = 0; t0 < NR; t0 += TPB) {
            const int o = b * NR + t0 + tid;
            float c2 = fminf(cd[o], sqdist(px[o], py[o], pz[o], ccx, ccy, ccz));
            cd[o] = c2;
            m = fmaxf(m, c2);
        }
        s_v[tid] = m;
        __syncthreads();
        for (int st = TPB / 2; st > 0; st >>= 1) {
            if (tid < st) s_v[tid] = fmaxf(s_v[tid], s_v[tid + st]);
            __syncthreads();
        }
        if (tid == 0) lb[b * 32] = s_v[0];
    }
}

// ---- stepB<R>: wave-parallel survivor rescans.
template <int R>
__global__ __launch_bounds__(TPB) void fps_stepB(
    const float* __restrict__ xyz, const float4* __restrict__ sel,
    float* __restrict__ ub, float* __restrict__ cd, int* __restrict__ ui,
    float* __restrict__ px, float* __restrict__ py, float* __restrict__ pz,
    const float* __restrict__ lb, unsigned long long* __restrict__ win)
{
    const int s = blockIdx.x, b = blockIdx.y, tid = threadIdx.x;
    const int lane = tid & 63, wv = tid >> 6;
    const float* xyzb = xyz + (size_t)b * NPTS * 3;
    __shared__ float scx[NPOINT], scy[NPOINT], scz[NPOINT];
    if (tid < R) {
        float4 q = sel[b * 16 + tid];
        scx[tid] = q.x; scy[tid] = q.y; scz[tid] = q.z;
    }
    __syncthreads();
    const float LB = lb[b * 32];
    unsigned long long* const wr = win + ((size_t)R * NB + b) * 16;

    const int r0 = s * 64 + wv * 16;
    for (int t = 0; t < 16; ++t) {
        const int rec = r0 + t, o = b * NR + rec;
        if (ub[o] < LB) continue;            // strict: ties stay scannable
        float v; int i;
        scanW<R>(xyzb, rec, lane, scx, scy, scz, v, i);
        if (lane == 0) {
            ub[o] = v; cd[o] = v; ui[o] = i;
            const float* qq = xyzb + (size_t)i * 3;
            px[o] = qq[0]; py[o] = qq[1]; pz[o] = qq[2];
            atomicMax(wr, packvi(v, i));
        }
    }
}

extern "C" void kernel_launch(void* const* d_in, const int* in_sizes, int n_in,
                              void* d_out, int out_size, void* d_ws, size_t ws_size,
                              hipStream_t stream) {
    const float* xyz = (const float*)d_in[0];
    int* out = (int*)d_out;
    char* ws = (char*)d_ws;

    float* ub = (float*)(ws + 0);            // 64*1024*4 = 256 KB each
    float* cd = (float*)(ws + (size_t)256 * 1024);
    int*   ui = (int*)  (ws + (size_t)512 * 1024);
    float* px = (float*)(ws + (size_t)768 * 1024);
    float* py = (float*)(ws + (size_t)1024 * 1024);
    float* pz = (float*)(ws + (size_t)1280 * 1024);
    float4* sel = (float4*)(ws + (size_t)1536 * 1024);            // 16 KB
    float* lb = (float*)(ws + (size_t)1552 * 1024);               //  8 KB
    unsigned long long* win = (unsigned long long*)(ws + (size_t)1560 * 1024); // 80 KB

    dim3 gA(NR / 4, NB), gB(16, NB), blk(TPB);
    fps_scan1<<<gA, blk, 0, stream>>>(xyz, ub, cd, ui, px, py, pz, win);

#define STEP(R) \
    fps_stepA<R><<<dim3(NB), blk, 0, stream>>>(xyz, out, sel, ub, cd, ui, px, py, pz, win, lb); \
    fps_stepB<R><<<gB, blk, 0, stream>>>(xyz, sel, ub, cd, ui, px, py, pz, lb, win);
    STEP(2) STEP(3) STEP(4) STEP(5) STEP(6) STEP(7) STEP(8) STEP(9)
#undef STEP
    fps_stepA<NPOINT><<<dim3(NB), blk, 0, stream>>>(xyz, out, sel, ub, cd, ui,
                                                    px, py, pz, win, lb);
}